// Round 2
// 6623.308 us; speedup vs baseline: 2.2670x; 2.2670x over previous
//
#include <hip/hip_runtime.h>

// LSTMDynamics v15b: B=64, T=512, D_IN=64, H=512, D_OUT=32.
// Same proven math/layout as v14 (register-resident fp16 weights, fp32 rings,
// fp32 epilogue, 256 blocks x 256 threads, layer skew). The change is the sync:
//
//   v14: one GLOBAL 256-block barrier per step, spin via atomicAdd RMW (convoy),
//        2x full __threadfence per step (trailing one by ALL threads).
//   v15: four INDEPENDENT per-mt group barriers (64 blocks each: 32 L0 + 32 L1),
//        each a MONOTONIC counter: arrive = release fetch_add(+1); wait =
//        relaxed atomic LOADS (no RMW convoy) until cnt >= 64*(s+1); then one
//        acquire fence. No reset round, no second flag.
//   v15b: fix compile — this ROCm lacks __hip_atomic_fence; use
//        __builtin_amdgcn_fence(__ATOMIC_ACQUIRE, "agent") instead.
//
// Correctness: all true deps and 2-slot-ring anti-deps of block (layer,mt,jt)
// close within group mt (rows are disjoint per mt; L0 (mt,jt) reads rows mt of
// ring0 written by L0 (mt,*); L1 (mt,jt) reads rows mt of ring0 [L0 (mt,*)] and
// ring1 [L1 (mt,*)]; slot s&1 overwrite kills h[s-2], whose readers are iter
// s-1 activities of the SAME group -> covered by cnt>=64*s). The epilogue reads
// all rows, so it waits for all four counters to reach 64*513 first.
// Release coverage: only wave0 issues global stores; thread0 (in wave0) does
// the release RMW after its epilogue -> wave-level vmcnt(0)+wbl2 covers all of
// wave0's lanes' stores. Acquire by thread0 + __syncthreads propagates
// visibility block-wide (same scope-promotion chain as proven v14 protocol).

#define T_    512
#define B_    64
#define H_    512
#define DIN_  64
#define NBLK  256
#define NTHR  256
#define SLOT  (B_ * H_)   // 32768 fp32 per ring slot, layout [b][k]

#if defined(__has_builtin)
#if __has_builtin(__builtin_amdgcn_fence)
#define ACQ_FENCE() __builtin_amdgcn_fence(__ATOMIC_ACQUIRE, "agent")
#else
#define ACQ_FENCE() __atomic_thread_fence(__ATOMIC_ACQUIRE)
#endif
#else
#define ACQ_FENCE() __atomic_thread_fence(__ATOMIC_ACQUIRE)
#endif

typedef _Float16 half8  __attribute__((ext_vector_type(8)));
typedef float    floatx4 __attribute__((ext_vector_type(4)));

__device__ inline float sigf(float x) { return 1.f / (1.f + __expf(-x)); }
__device__ inline float tanhf_(float x) {
    if (x >  9.f) return  1.f;
    if (x < -9.f) return -1.f;
    const float e = __expf(2.f * x);
    return (e - 1.f) / (e + 1.f);
}
__device__ inline float4 ld4(const float* p) { return *(const float4*)p; }

// fp32[8] -> fp16 MFMA fragment
__device__ inline half8 frag8(const float* p) {
    const float4 a = ld4(p), b = ld4(p + 4);
    half8 r;
    r[0] = (_Float16)a.x; r[1] = (_Float16)a.y; r[2] = (_Float16)a.z; r[3] = (_Float16)a.w;
    r[4] = (_Float16)b.x; r[5] = (_Float16)b.y; r[6] = (_Float16)b.z; r[7] = (_Float16)b.w;
    return r;
}

// Monotonic group barrier. cnt is this group's counter (own 128B line).
// All threads call; thread0 arrives (release) and spins on relaxed LOADS.
__device__ inline void group_sync(unsigned* cnt, unsigned target) {
    if (threadIdx.x == 0) {
        __hip_atomic_fetch_add(cnt, 1u, __ATOMIC_RELEASE, __HIP_MEMORY_SCOPE_AGENT);
        while (__hip_atomic_load(cnt, __ATOMIC_RELAXED, __HIP_MEMORY_SCOPE_AGENT) < target)
            __builtin_amdgcn_s_sleep(1);
        ACQ_FENCE();
    }
    __syncthreads();
}

// MFMA 16x16x32 f16 fragment layout (proven by R2<->R5 bit-agreement):
//   A: a[j] = A[m = lane&15][k = (lane>>4)*8 + j]
//   B: b[j] = B[k = (lane>>4)*8 + j][n = lane&15]
//   D: d[r] = D[m = (lane>>4)*4 + r][n = lane&15]
__global__ __launch_bounds__(NTHR) void lstm_v15(
    const float* __restrict__ x,
    const float* __restrict__ Wih0, const float* __restrict__ Whh0,
    const float* __restrict__ bih0, const float* __restrict__ bhh0,
    const float* __restrict__ Wih1, const float* __restrict__ Whh1,
    const float* __restrict__ bih1, const float* __restrict__ bhh1,
    const float* __restrict__ Wout, const float* __restrict__ bout,
    float* __restrict__ out,
    unsigned* bar,
    float* ring0,       // 2 slots [64][512] fp32
    float* ring1)       // 2 slots [64][512] fp32
{
    const int tid   = threadIdx.x;
    const int wave  = tid >> 6;
    const int lane  = tid & 63;
    const int l15   = lane & 15;
    const int quad  = lane >> 4;
    const int blk   = blockIdx.x;
    const int layer = blk >> 7;        // 0: blocks 0..127, 1: blocks 128..255
    const int id    = blk & 127;
    const int mt    = id >> 5;         // batch tile (4 x 16)
    const int jt    = id & 31;         // column tile (32 x 16)

    unsigned* cnt = bar + (mt << 5);   // group counter, one 128B line per mt

    __shared__ float red[3][4][4][64]; // partials from waves 1..3

    // Combined biases: wave0 lanes own column jt*16 + l15.
    float bsi = 0.f, bsf = 0.f, bsg = 0.f, bso = 0.f;
    if (wave == 0) {
        const int j = jt * 16 + l15;
        const float* bi = layer ? bih1 : bih0;
        const float* bh = layer ? bhh1 : bhh0;
        bsi = bi[j]        + bh[j];
        bsf = bi[512 + j]  + bh[512 + j];
        bsg = bi[1024 + j] + bh[1024 + j];
        bso = bi[1536 + j] + bh[1536 + j];
    }

    float cst[4] = {0.f, 0.f, 0.f, 0.f};  // cell state: 4 batch rows x 1 col / lane

    if (layer == 0) {
        // Layer 0: A = [x_t (K 0..63) | h0_{s-1} (K 64..575)], 18 chunks of 32.
        const int cstart = (wave < 2) ? wave * 5 : 10 + (wave - 2) * 4;
        const int cnt_c  = (wave < 2) ? 5 : 4;
        half8 bf[4][5];
        #pragma unroll
        for (int g = 0; g < 4; ++g) {
            const int n = g * 512 + jt * 16 + l15;   // gate row (i,f,g,o)
            #pragma unroll
            for (int cc = 0; cc < 5; ++cc) {
                if (cc < cnt_c) {
                    const int c = cstart + cc;
                    const float* src = (c < 2)
                        ? (Wih0 + n * 64  + c * 32 + quad * 8)
                        : (Whh0 + n * 512 + (c - 2) * 32 + quad * 8);
                    bf[g][cc] = frag8(src);
                }
            }
        }

        for (int s = 0; s <= T_; ++s) {
            const bool active = (s < T_);
            floatx4 acc[4] = { {0.f,0.f,0.f,0.f}, {0.f,0.f,0.f,0.f},
                               {0.f,0.f,0.f,0.f}, {0.f,0.f,0.f,0.f} };
            if (active) {
                const float* h0prev = ring0 + ((s + 1) & 1) * SLOT;  // slot (s-1)&1; s=0 -> zeros
                const int arow = mt * 16 + l15;
                #pragma unroll
                for (int cc = 0; cc < 5; ++cc) {
                    if (cc < cnt_c) {
                        const int c = cstart + cc;
                        half8 a;
                        if (c < 2) a = frag8(x + (arow * T_ + s) * DIN_ + c * 32 + quad * 8);
                        else       a = frag8(h0prev + arow * H_ + (c - 2) * 32 + quad * 8);
                        acc[0] = __builtin_amdgcn_mfma_f32_16x16x32_f16(a, bf[0][cc], acc[0], 0, 0, 0);
                        acc[1] = __builtin_amdgcn_mfma_f32_16x16x32_f16(a, bf[1][cc], acc[1], 0, 0, 0);
                        acc[2] = __builtin_amdgcn_mfma_f32_16x16x32_f16(a, bf[2][cc], acc[2], 0, 0, 0);
                        acc[3] = __builtin_amdgcn_mfma_f32_16x16x32_f16(a, bf[3][cc], acc[3], 0, 0, 0);
                    }
                }
                if (wave != 0) {
                    #pragma unroll
                    for (int g = 0; g < 4; ++g)
                        #pragma unroll
                        for (int r = 0; r < 4; ++r)
                            red[wave - 1][g][r][lane] = acc[g][r];
                }
            }
            __syncthreads();
            if (active && wave == 0) {
                #pragma unroll
                for (int g = 0; g < 4; ++g)
                    #pragma unroll
                    for (int r = 0; r < 4; ++r)
                        acc[g][r] += red[0][g][r][lane] + red[1][g][r][lane] + red[2][g][r][lane];
                float* hdst = ring0 + (s & 1) * SLOT;
                #pragma unroll
                for (int r = 0; r < 4; ++r) {
                    const float ig = sigf(acc[0][r] + bsi);
                    const float fg = sigf(acc[1][r] + bsf);
                    const float gg = tanhf_(acc[2][r] + bsg);
                    const float og = sigf(acc[3][r] + bso);
                    const float cn = fg * cst[r] + ig * gg;
                    cst[r] = cn;
                    hdst[(mt * 16 + quad * 4 + r) * H_ + jt * 16 + l15] = og * tanhf_(cn);
                }
            }
            group_sync(cnt, 64u * (unsigned)(s + 1));
        }
    } else {
        // Layer 1 at tau = s-1: A = [h0_tau (K 0..511) | h1_{tau-1} (K 512..1023)].
        half8 bf[4][8];
        #pragma unroll
        for (int g = 0; g < 4; ++g) {
            const int n = g * 512 + jt * 16 + l15;
            #pragma unroll
            for (int cc = 0; cc < 8; ++cc) {
                const int c = wave * 8 + cc;              // 0..31
                const float* src = (c < 16)
                    ? (Wih1 + n * 512 + c * 32 + quad * 8)
                    : (Whh1 + n * 512 + (c - 16) * 32 + quad * 8);
                bf[g][cc] = frag8(src);
            }
        }

        for (int s = 0; s <= T_; ++s) {
            const bool active = (s >= 1);
            const int tau = s - 1;
            floatx4 acc[4] = { {0.f,0.f,0.f,0.f}, {0.f,0.f,0.f,0.f},
                               {0.f,0.f,0.f,0.f}, {0.f,0.f,0.f,0.f} };
            if (active) {
                const float* h0cur  = ring0 + (tau & 1) * SLOT;        // h0_tau
                const float* h1prev = ring1 + ((tau + 1) & 1) * SLOT;  // h1_{tau-1}; tau=0 -> zeros
                const int arow = mt * 16 + l15;
                const float* rb0 = h0cur  + arow * H_;
                const float* rb1 = h1prev + arow * H_;
                #pragma unroll
                for (int cc = 0; cc < 8; ++cc) {
                    const int c = wave * 8 + cc;
                    const half8 a = (c < 16) ? frag8(rb0 + c * 32 + quad * 8)
                                             : frag8(rb1 + (c - 16) * 32 + quad * 8);
                    acc[0] = __builtin_amdgcn_mfma_f32_16x16x32_f16(a, bf[0][cc], acc[0], 0, 0, 0);
                    acc[1] = __builtin_amdgcn_mfma_f32_16x16x32_f16(a, bf[1][cc], acc[1], 0, 0, 0);
                    acc[2] = __builtin_amdgcn_mfma_f32_16x16x32_f16(a, bf[2][cc], acc[2], 0, 0, 0);
                    acc[3] = __builtin_amdgcn_mfma_f32_16x16x32_f16(a, bf[3][cc], acc[3], 0, 0, 0);
                }
                if (wave != 0) {
                    #pragma unroll
                    for (int g = 0; g < 4; ++g)
                        #pragma unroll
                        for (int r = 0; r < 4; ++r)
                            red[wave - 1][g][r][lane] = acc[g][r];
                }
            }
            __syncthreads();
            if (active && wave == 0) {
                #pragma unroll
                for (int g = 0; g < 4; ++g)
                    #pragma unroll
                    for (int r = 0; r < 4; ++r)
                        acc[g][r] += red[0][g][r][lane] + red[1][g][r][lane] + red[2][g][r][lane];
                float* hdst = ring1 + (tau & 1) * SLOT;
                #pragma unroll
                for (int r = 0; r < 4; ++r) {
                    const float ig = sigf(acc[0][r] + bsi);
                    const float fg = sigf(acc[1][r] + bsf);
                    const float gg = tanhf_(acc[2][r] + bsg);
                    const float og = sigf(acc[3][r] + bso);
                    const float cn = fg * cst[r] + ig * gg;
                    cst[r] = cn;
                    hdst[(mt * 16 + quad * 4 + r) * H_ + jt * 16 + l15] = og * tanhf_(cn);
                }
            }
            group_sync(cnt, 64u * (unsigned)(s + 1));
        }
    }

    // Wait for ALL groups (epilogue reads rows from every mt).
    if (tid == 0) {
        #pragma unroll
        for (int g = 0; g < 4; ++g) {
            unsigned* cg = bar + (g << 5);
            while (__hip_atomic_load(cg, __ATOMIC_RELAXED, __HIP_MEMORY_SCOPE_AGENT)
                   < 64u * (unsigned)(T_ + 1))
                __builtin_amdgcn_s_sleep(1);
        }
        ACQ_FENCE();
    }
    __syncthreads();

    // Epilogue: y[b][d] = h1_511[b][:] . Wout[d][:] + bout[d]  (fp32 out).
    // h1_511 = ring1 slot (511&1)=1 (fp32), published by the final group_sync.
    {
        const float* h1fin = ring1 + SLOT;
        const int gid = blk * NTHR + tid;   // 0..65535
        const int o   = gid >> 5;           // 0..2047
        const int sub = gid & 31;
        const int ob  = o >> 5;
        const int od  = o & 31;
        float p = 0.f;
        const float* hb = h1fin + ob * H_ + sub * 16;
        const float* wb = Wout  + od * H_ + sub * 16;
        #pragma unroll
        for (int k = 0; k < 16; ++k) p += hb[k] * wb[k];
        p += __shfl_xor(p, 16);
        p += __shfl_xor(p, 8);
        p += __shfl_xor(p, 4);
        p += __shfl_xor(p, 2);
        p += __shfl_xor(p, 1);
        if (sub == 0) out[o] = p + bout[od];
    }
}

extern "C" void kernel_launch(void* const* d_in, const int* in_sizes, int n_in,
                              void* d_out, int out_size, void* d_ws, size_t ws_size,
                              hipStream_t stream) {
    (void)in_sizes; (void)n_in; (void)out_size; (void)ws_size;
    const float* x    = (const float*)d_in[0];
    const float* Wih0 = (const float*)d_in[1];
    const float* Whh0 = (const float*)d_in[2];
    const float* bih0 = (const float*)d_in[3];
    const float* bhh0 = (const float*)d_in[4];
    const float* Wih1 = (const float*)d_in[5];
    const float* Whh1 = (const float*)d_in[6];
    const float* bih1 = (const float*)d_in[7];
    const float* bhh1 = (const float*)d_in[8];
    const float* Wout = (const float*)d_in[9];
    const float* bout = (const float*)d_in[10];

    unsigned char* ws = (unsigned char*)d_ws;
    unsigned* bar = (unsigned*)ws;                      // 1 KB: 4 group counters, 128B apart
    float* ring0  = (float*)(ws + 1024);                // 2 slots x 128 KB
    float* ring1  = (float*)(ws + 1024 + 2 * SLOT * 4); // 2 slots x 128 KB
    // Zero counters + both rings (slot1 of each must read as h_{-1}=0).
    hipMemsetAsync(ws, 0, 1024 + 4 * SLOT * 4, stream);

    lstm_v15<<<dim3(NBLK), dim3(NTHR), 0, stream>>>(
        x, Wih0, Whh0, bih0, bhh0, Wih1, Whh1, bih1, bhh1, Wout, bout,
        (float*)d_out, bar, ring0, ring1);
}

// Round 3
// 6497.259 us; speedup vs baseline: 2.3110x; 1.0194x over previous
//
#include <hip/hip_runtime.h>

// LSTMDynamics v16: B=64, T=512, D_IN=64, H=512, D_OUT=32.
// Same proven math/decomposition as v14/v15 (register fp16 weights, K-split
// across 4 waves + LDS reduce, wave0 gate math, layer skew, 256 blocks).
// Sync rework #2 — remove ALL per-step cache maintenance:
//   v15: per-step RELEASE fetch_add (emits s_waitcnt+buffer_wbl2: full XCD-L2
//        dirty writeback) + ACQUIRE fence (buffer_inv: full L2 invalidate),
//        per block per step; one counter per mt (64-wide barrier).
//   v16: ring h data uses relaxed SYSTEM-scope loads/stores (sc0 sc1 — per-
//        access read/write-through at the device coherence point). NO fences.
//        Producer order: explicit s_waitcnt vmcnt(0), then RELAXED fetch_add.
//        Counters split per (layer, mt): 8 monotonic counters, 32 producers
//        each. ring0 has 4 slots so L0 runs up to 2 steps ahead of L1; L1 (the
//        throughput chain) then never blocks on L0 in steady state.
// Dependency algebra (cnt = arrivals; after a layer's blocks finish iter k,
// its counter = 32*(k+1); both layers arrive on EVERY iter s=0..512):
//   L0 iter s: needs L0 peers thru s-1  -> cnt0 >= 32s
//              write slot s%4 kills h0[s-4], read by L0@s-3 and L1@s-3
//                                        -> cnt1 >= 32(s-2)   [guard s>=2]
//   L1 iter s (tau=s-1): h0[tau] ready  -> cnt0 >= 32s
//              h1[s-2] ready (peers)    -> cnt1 >= 32s (also covers 2-slot
//              ring1 anti-dep, same condition)
//   epilogue: h1[511] from all mt       -> cnt1[g] >= 32*513 for all g
// x and weights stay on the normal cached path (never invalidated now).

#define T_    512
#define B_    64
#define H_    512
#define DIN_  64
#define NBLK  256
#define NTHR  256
#define SLOT  (B_ * H_)   // 32768 fp32 per ring slot, layout [b][k]
#define R0S   4           // ring0 slots (layer-0 lookahead)

typedef _Float16 half8  __attribute__((ext_vector_type(8)));
typedef float    floatx4 __attribute__((ext_vector_type(4)));

__device__ inline float sigf(float x) { return 1.f / (1.f + __expf(-x)); }
__device__ inline float tanhf_(float x) {
    if (x >  9.f) return  1.f;
    if (x < -9.f) return -1.f;
    const float e = __expf(2.f * x);
    return (e - 1.f) / (e + 1.f);
}
__device__ inline float4 ld4(const float* p) { return *(const float4*)p; }

// fp32[8] -> fp16 MFMA fragment, normal cached path (weights, x).
__device__ inline half8 frag8(const float* p) {
    const float4 a = ld4(p), b = ld4(p + 4);
    half8 r;
    r[0] = (_Float16)a.x; r[1] = (_Float16)a.y; r[2] = (_Float16)a.z; r[3] = (_Float16)a.w;
    r[4] = (_Float16)b.x; r[5] = (_Float16)b.y; r[6] = (_Float16)b.z; r[7] = (_Float16)b.w;
    return r;
}

// fp32[8] -> fp16 fragment via SYSTEM-scope read-through loads (ring data).
__device__ inline half8 frag8_sys(const float* p) {
    float v[8];
    #pragma unroll
    for (int i = 0; i < 8; ++i)
        v[i] = __hip_atomic_load(p + i, __ATOMIC_RELAXED, __HIP_MEMORY_SCOPE_SYSTEM);
    half8 r;
    #pragma unroll
    for (int i = 0; i < 8; ++i) r[i] = (_Float16)v[i];
    return r;
}

__device__ inline void st_sys(float* p, float v) {
    __hip_atomic_store(p, v, __ATOMIC_RELAXED, __HIP_MEMORY_SCOPE_SYSTEM);
}

// Arrive: drain this wave's (write-through) stores, then relaxed bump.
__device__ inline void arrive(unsigned* c) {
    asm volatile("s_waitcnt vmcnt(0)" ::: "memory");
    __hip_atomic_fetch_add(c, 1u, __ATOMIC_RELAXED, __HIP_MEMORY_SCOPE_AGENT);
}

// Spin on relaxed loads (no RMW convoy, no fence — data path is self-coherent).
__device__ inline void wait_ge(unsigned* c, unsigned tgt) {
    while (__hip_atomic_load(c, __ATOMIC_RELAXED, __HIP_MEMORY_SCOPE_AGENT) < tgt)
        __builtin_amdgcn_s_sleep(1);
}

// MFMA 16x16x32 f16 fragment layout (proven by R2<->R5 bit-agreement):
//   A: a[j] = A[m = lane&15][k = (lane>>4)*8 + j]
//   B: b[j] = B[k = (lane>>4)*8 + j][n = lane&15]
//   D: d[r] = D[m = (lane>>4)*4 + r][n = lane&15]
__global__ __launch_bounds__(NTHR) void lstm_v16(
    const float* __restrict__ x,
    const float* __restrict__ Wih0, const float* __restrict__ Whh0,
    const float* __restrict__ bih0, const float* __restrict__ bhh0,
    const float* __restrict__ Wih1, const float* __restrict__ Whh1,
    const float* __restrict__ bih1, const float* __restrict__ bhh1,
    const float* __restrict__ Wout, const float* __restrict__ bout,
    float* __restrict__ out,
    unsigned* bar,
    float* ring0,       // R0S slots [64][512] fp32
    float* ring1)       // 2 slots [64][512] fp32
{
    const int tid   = threadIdx.x;
    const int wave  = tid >> 6;
    const int lane  = tid & 63;
    const int l15   = lane & 15;
    const int quad  = lane >> 4;
    const int blk   = blockIdx.x;
    const int layer = blk >> 7;        // 0: blocks 0..127, 1: blocks 128..255
    const int id    = blk & 127;
    const int mt    = id >> 5;         // batch tile (4 x 16)
    const int jt    = id & 31;         // column tile (32 x 16)

    unsigned* cnt0 = bar + (mt << 5);        // layer-0 counter for group mt
    unsigned* cnt1 = bar + ((4 + mt) << 5);  // layer-1 counter for group mt

    __shared__ float red[3][4][4][64]; // partials from waves 1..3

    // Combined biases: wave0 lanes own column jt*16 + l15.
    float bsi = 0.f, bsf = 0.f, bsg = 0.f, bso = 0.f;
    if (wave == 0) {
        const int j = jt * 16 + l15;
        const float* bi = layer ? bih1 : bih0;
        const float* bh = layer ? bhh1 : bhh0;
        bsi = bi[j]        + bh[j];
        bsf = bi[512 + j]  + bh[512 + j];
        bsg = bi[1024 + j] + bh[1024 + j];
        bso = bi[1536 + j] + bh[1536 + j];
    }

    float cst[4] = {0.f, 0.f, 0.f, 0.f};  // cell state: 4 batch rows x 1 col / lane

    if (layer == 0) {
        // Layer 0: A = [x_t (K 0..63) | h0_{s-1} (K 64..575)], 18 chunks of 32.
        const int cstart = (wave < 2) ? wave * 5 : 10 + (wave - 2) * 4;
        const int cnt_c  = (wave < 2) ? 5 : 4;
        half8 bf[4][5];
        #pragma unroll
        for (int g = 0; g < 4; ++g) {
            const int n = g * 512 + jt * 16 + l15;   // gate row (i,f,g,o)
            #pragma unroll
            for (int cc = 0; cc < 5; ++cc) {
                if (cc < cnt_c) {
                    const int c = cstart + cc;
                    const float* src = (c < 2)
                        ? (Wih0 + n * 64  + c * 32 + quad * 8)
                        : (Whh0 + n * 512 + (c - 2) * 32 + quad * 8);
                    bf[g][cc] = frag8(src);
                }
            }
        }

        for (int s = 0; s <= T_; ++s) {
            if (tid == 0) {
                wait_ge(cnt0, 32u * (unsigned)s);                       // peers thru s-1
                if (s >= 2) wait_ge(cnt1, 32u * (unsigned)(s - 2));     // ring0 anti-dep
            }
            __syncthreads();   // gates every wave's ring loads on data-ready
            const bool active = (s < T_);
            floatx4 acc[4] = { {0.f,0.f,0.f,0.f}, {0.f,0.f,0.f,0.f},
                               {0.f,0.f,0.f,0.f}, {0.f,0.f,0.f,0.f} };
            if (active) {
                const float* h0prev = ring0 + ((s + R0S - 1) & (R0S - 1)) * SLOT; // slot (s-1)%4
                const int arow = mt * 16 + l15;
                #pragma unroll
                for (int cc = 0; cc < 5; ++cc) {
                    if (cc < cnt_c) {
                        const int c = cstart + cc;
                        half8 a;
                        if (c < 2) a = frag8(x + (arow * T_ + s) * DIN_ + c * 32 + quad * 8);
                        else       a = frag8_sys(h0prev + arow * H_ + (c - 2) * 32 + quad * 8);
                        acc[0] = __builtin_amdgcn_mfma_f32_16x16x32_f16(a, bf[0][cc], acc[0], 0, 0, 0);
                        acc[1] = __builtin_amdgcn_mfma_f32_16x16x32_f16(a, bf[1][cc], acc[1], 0, 0, 0);
                        acc[2] = __builtin_amdgcn_mfma_f32_16x16x32_f16(a, bf[2][cc], acc[2], 0, 0, 0);
                        acc[3] = __builtin_amdgcn_mfma_f32_16x16x32_f16(a, bf[3][cc], acc[3], 0, 0, 0);
                    }
                }
                if (wave != 0) {
                    #pragma unroll
                    for (int g = 0; g < 4; ++g)
                        #pragma unroll
                        for (int r = 0; r < 4; ++r)
                            red[wave - 1][g][r][lane] = acc[g][r];
                }
            }
            __syncthreads();
            if (active && wave == 0) {
                #pragma unroll
                for (int g = 0; g < 4; ++g)
                    #pragma unroll
                    for (int r = 0; r < 4; ++r)
                        acc[g][r] += red[0][g][r][lane] + red[1][g][r][lane] + red[2][g][r][lane];
                float* hdst = ring0 + (s & (R0S - 1)) * SLOT;
                #pragma unroll
                for (int r = 0; r < 4; ++r) {
                    const float ig = sigf(acc[0][r] + bsi);
                    const float fg = sigf(acc[1][r] + bsf);
                    const float gg = tanhf_(acc[2][r] + bsg);
                    const float og = sigf(acc[3][r] + bso);
                    const float cn = fg * cst[r] + ig * gg;
                    cst[r] = cn;
                    st_sys(hdst + (mt * 16 + quad * 4 + r) * H_ + jt * 16 + l15,
                           og * tanhf_(cn));
                }
            }
            if (tid == 0) arrive(cnt0);  // thread0 is in wave0: vmcnt drains all h stores
        }
    } else {
        // Layer 1 at tau = s-1: A = [h0_tau (K 0..511) | h1_{tau-1} (K 512..1023)].
        half8 bf[4][8];
        #pragma unroll
        for (int g = 0; g < 4; ++g) {
            const int n = g * 512 + jt * 16 + l15;
            #pragma unroll
            for (int cc = 0; cc < 8; ++cc) {
                const int c = wave * 8 + cc;              // 0..31
                const float* src = (c < 16)
                    ? (Wih1 + n * 512 + c * 32 + quad * 8)
                    : (Whh1 + n * 512 + (c - 16) * 32 + quad * 8);
                bf[g][cc] = frag8(src);
            }
        }

        for (int s = 0; s <= T_; ++s) {
            if (tid == 0) {
                wait_ge(cnt0, 32u * (unsigned)s);   // h0[s-1] published
                wait_ge(cnt1, 32u * (unsigned)s);   // h1[s-2] published (+ anti-dep)
            }
            __syncthreads();
            const bool active = (s >= 1);
            const int tau = s - 1;
            floatx4 acc[4] = { {0.f,0.f,0.f,0.f}, {0.f,0.f,0.f,0.f},
                               {0.f,0.f,0.f,0.f}, {0.f,0.f,0.f,0.f} };
            if (active) {
                const float* h0cur  = ring0 + (tau & (R0S - 1)) * SLOT;  // h0_tau
                const float* h1prev = ring1 + ((tau + 1) & 1) * SLOT;    // h1_{tau-1}; tau=0 -> zeros
                const int arow = mt * 16 + l15;
                const float* rb0 = h0cur  + arow * H_;
                const float* rb1 = h1prev + arow * H_;
                #pragma unroll
                for (int cc = 0; cc < 8; ++cc) {
                    const int c = wave * 8 + cc;
                    const half8 a = (c < 16) ? frag8_sys(rb0 + c * 32 + quad * 8)
                                             : frag8_sys(rb1 + (c - 16) * 32 + quad * 8);
                    acc[0] = __builtin_amdgcn_mfma_f32_16x16x32_f16(a, bf[0][cc], acc[0], 0, 0, 0);
                    acc[1] = __builtin_amdgcn_mfma_f32_16x16x32_f16(a, bf[1][cc], acc[1], 0, 0, 0);
                    acc[2] = __builtin_amdgcn_mfma_f32_16x16x32_f16(a, bf[2][cc], acc[2], 0, 0, 0);
                    acc[3] = __builtin_amdgcn_mfma_f32_16x16x32_f16(a, bf[3][cc], acc[3], 0, 0, 0);
                }
                if (wave != 0) {
                    #pragma unroll
                    for (int g = 0; g < 4; ++g)
                        #pragma unroll
                        for (int r = 0; r < 4; ++r)
                            red[wave - 1][g][r][lane] = acc[g][r];
                }
            }
            __syncthreads();
            if (active && wave == 0) {
                #pragma unroll
                for (int g = 0; g < 4; ++g)
                    #pragma unroll
                    for (int r = 0; r < 4; ++r)
                        acc[g][r] += red[0][g][r][lane] + red[1][g][r][lane] + red[2][g][r][lane];
                float* hdst = ring1 + (tau & 1) * SLOT;
                #pragma unroll
                for (int r = 0; r < 4; ++r) {
                    const float ig = sigf(acc[0][r] + bsi);
                    const float fg = sigf(acc[1][r] + bsf);
                    const float gg = tanhf_(acc[2][r] + bsg);
                    const float og = sigf(acc[3][r] + bso);
                    const float cn = fg * cst[r] + ig * gg;
                    cst[r] = cn;
                    st_sys(hdst + (mt * 16 + quad * 4 + r) * H_ + jt * 16 + l15,
                           og * tanhf_(cn));
                }
            }
            if (tid == 0) arrive(cnt1);
        }
    }

    // Wait for ALL layer-1 groups (epilogue reads h1_511 rows from every mt).
    if (tid == 0) {
        #pragma unroll
        for (int g = 0; g < 4; ++g)
            wait_ge(bar + ((4 + g) << 5), 32u * (unsigned)(T_ + 1));
    }
    __syncthreads();

    // Epilogue: y[b][d] = h1_511[b][:] . Wout[d][:] + bout[d]  (fp32 out).
    // h1_511 = ring1 slot (511&1)=1; read via system-scope loads.
    {
        const float* h1fin = ring1 + SLOT;
        const int gid = blk * NTHR + tid;   // 0..65535
        const int o   = gid >> 5;           // 0..2047
        const int sub = gid & 31;
        const int ob  = o >> 5;
        const int od  = o & 31;
        float p = 0.f;
        const float* hb = h1fin + ob * H_ + sub * 16;
        const float* wb = Wout  + od * H_ + sub * 16;
        #pragma unroll
        for (int k = 0; k < 16; ++k)
            p += __hip_atomic_load(hb + k, __ATOMIC_RELAXED, __HIP_MEMORY_SCOPE_SYSTEM) * wb[k];
        p += __shfl_xor(p, 16);
        p += __shfl_xor(p, 8);
        p += __shfl_xor(p, 4);
        p += __shfl_xor(p, 2);
        p += __shfl_xor(p, 1);
        if (sub == 0) out[o] = p + bout[od];
    }
}

extern "C" void kernel_launch(void* const* d_in, const int* in_sizes, int n_in,
                              void* d_out, int out_size, void* d_ws, size_t ws_size,
                              hipStream_t stream) {
    (void)in_sizes; (void)n_in; (void)out_size; (void)ws_size;
    const float* x    = (const float*)d_in[0];
    const float* Wih0 = (const float*)d_in[1];
    const float* Whh0 = (const float*)d_in[2];
    const float* bih0 = (const float*)d_in[3];
    const float* bhh0 = (const float*)d_in[4];
    const float* Wih1 = (const float*)d_in[5];
    const float* Whh1 = (const float*)d_in[6];
    const float* bih1 = (const float*)d_in[7];
    const float* bhh1 = (const float*)d_in[8];
    const float* Wout = (const float*)d_in[9];
    const float* bout = (const float*)d_in[10];

    unsigned char* ws = (unsigned char*)d_ws;
    unsigned* bar = (unsigned*)ws;                        // 1 KB: 8 counters, 128B apart
    float* ring0  = (float*)(ws + 1024);                  // R0S slots x 128 KB
    float* ring1  = (float*)(ws + 1024 + R0S * SLOT * 4); // 2 slots x 128 KB
    // Zero counters + rings (ring0 slot3 and ring1 slot1 must read as h_{-1}=0).
    hipMemsetAsync(ws, 0, 1024 + (R0S + 2) * SLOT * 4, stream);

    lstm_v16<<<dim3(NBLK), dim3(NTHR), 0, stream>>>(
        x, Wih0, Whh0, bih0, bhh0, Wih1, Whh1, bih1, bhh1, Wout, bout,
        (float*)d_out, bar, ring0, ring1);
}

// Round 4
// 5326.579 us; speedup vs baseline: 2.8189x; 1.2198x over previous
//
#include <hip/hip_runtime.h>

// LSTMDynamics v17: B=64, T=512, D_IN=64, H=512, D_OUT=32.
// Same proven math as v14-v16 (register fp16 weights, K-split across 4 waves +
// LDS reduce, wave0 gate math, layer skew, 4-slot ring0 lookahead, sys-scope
// ring data). Sync rework #3 — kill the RMW convoy and serial detection:
//
//   v16: per-(layer,mt) monotonic counter, 32 producers fetch_add the SAME
//        dword (memory-side RMWs serialize, and queue behind ~64 consumers'
//        spin loads); consumer = scalar thread0 poll.
//   v17: per-PRODUCER flag words. Producer (layer,mt,jt) stores s+1 to its own
//        dword in a 32-dword line (parallel, no RMW). Consumer = wave0 ballot:
//        one coalesced global_load_dword of the line (lane&31) + __all().
//        Layer1 split-wait: waves 0-1 (h0 chunks) start loads+MFMA after the
//        flags0 wait, overlapping the critical flags1 wait; waves 2-3 (h1
//        chunks) proceed after flags1.
//
// Dependency algebra (flag = iterations completed; producer stores s+1 after
// finishing iter s; "all peers finished iter k" <=> line all >= k+1):
//   L0 iter s: peers thru s-1 -> f0 >= s; ring0 slot s%4 kills h0[s-4], last
//              read by L1 iter s-3 -> f1 >= s-2 (guard s>=2).
//   L1 iter s (tau=s-1): h0[tau] -> f0 >= s; h1[tau-1] + ring1 anti-dep
//              -> f1 >= s.
//   epilogue: h1[511] from all mt -> f1[g] >= 513 for all g.
// Producer order: s_waitcnt vmcnt(0) (drain wave0's write-through h stores)
// then relaxed sys-scope flag store. Consumer: ballot-load feeds the exit
// branch; h loads issue only after, plus __syncthreads for other waves.

#define T_    512
#define B_    64
#define H_    512
#define DIN_  64
#define NBLK  256
#define NTHR  256
#define SLOT  (B_ * H_)   // 32768 fp32 per ring slot, layout [b][k]
#define R0S   4           // ring0 slots (layer-0 lookahead)

typedef _Float16 half8  __attribute__((ext_vector_type(8)));
typedef float    floatx4 __attribute__((ext_vector_type(4)));

__device__ inline float sigf(float x) { return 1.f / (1.f + __expf(-x)); }
__device__ inline float tanhf_(float x) {
    if (x >  9.f) return  1.f;
    if (x < -9.f) return -1.f;
    const float e = __expf(2.f * x);
    return (e - 1.f) / (e + 1.f);
}
__device__ inline float4 ld4(const float* p) { return *(const float4*)p; }

// fp32[8] -> fp16 MFMA fragment, normal cached path (weights, x).
__device__ inline half8 frag8(const float* p) {
    const float4 a = ld4(p), b = ld4(p + 4);
    half8 r;
    r[0] = (_Float16)a.x; r[1] = (_Float16)a.y; r[2] = (_Float16)a.z; r[3] = (_Float16)a.w;
    r[4] = (_Float16)b.x; r[5] = (_Float16)b.y; r[6] = (_Float16)b.z; r[7] = (_Float16)b.w;
    return r;
}

// fp32[8] -> fp16 fragment via SYSTEM-scope read-through loads (ring data).
__device__ inline half8 frag8_sys(const float* p) {
    float v[8];
    #pragma unroll
    for (int i = 0; i < 8; ++i)
        v[i] = __hip_atomic_load(p + i, __ATOMIC_RELAXED, __HIP_MEMORY_SCOPE_SYSTEM);
    half8 r;
    #pragma unroll
    for (int i = 0; i < 8; ++i) r[i] = (_Float16)v[i];
    return r;
}

__device__ inline void st_sys(float* p, float v) {
    __hip_atomic_store(p, v, __ATOMIC_RELAXED, __HIP_MEMORY_SCOPE_SYSTEM);
}
__device__ inline void st_sys_u(unsigned* p, unsigned v) {
    __hip_atomic_store(p, v, __ATOMIC_RELAXED, __HIP_MEMORY_SCOPE_SYSTEM);
}

// Wave-parallel flag wait: all 64 lanes load flags[lane&31] (one coalesced
// 128B line read), exit when every producer's flag >= tgt.
__device__ inline void wait_flags(unsigned* line, unsigned tgt, int lane) {
    for (;;) {
        const unsigned v = __hip_atomic_load(line + (lane & 31),
                                             __ATOMIC_RELAXED, __HIP_MEMORY_SCOPE_SYSTEM);
        if (__all((int)(v >= tgt))) return;
        __builtin_amdgcn_s_sleep(1);
    }
}

// MFMA 16x16x32 f16 fragment layout (proven by R2<->R5 bit-agreement):
//   A: a[j] = A[m = lane&15][k = (lane>>4)*8 + j]
//   B: b[j] = B[k = (lane>>4)*8 + j][n = lane&15]
//   D: d[r] = D[m = (lane>>4)*4 + r][n = lane&15]
__global__ __launch_bounds__(NTHR) void lstm_v17(
    const float* __restrict__ x,
    const float* __restrict__ Wih0, const float* __restrict__ Whh0,
    const float* __restrict__ bih0, const float* __restrict__ bhh0,
    const float* __restrict__ Wih1, const float* __restrict__ Whh1,
    const float* __restrict__ bih1, const float* __restrict__ bhh1,
    const float* __restrict__ Wout, const float* __restrict__ bout,
    float* __restrict__ out,
    unsigned* bar,
    float* ring0,       // R0S slots [64][512] fp32
    float* ring1)       // 2 slots [64][512] fp32
{
    const int tid   = threadIdx.x;
    const int wave  = tid >> 6;
    const int lane  = tid & 63;
    const int l15   = lane & 15;
    const int quad  = lane >> 4;
    const int blk   = blockIdx.x;
    const int layer = blk >> 7;        // 0: blocks 0..127, 1: blocks 128..255
    const int id    = blk & 127;
    const int mt    = id >> 5;         // batch tile (4 x 16)
    const int jt    = id & 31;         // column tile (32 x 16)

    unsigned* f0 = bar + (mt << 6);        // L0 flag line for group mt (32 dwords)
    unsigned* f1 = bar + ((4 + mt) << 6);  // L1 flag line for group mt

    __shared__ float red[3][4][4][64]; // partials from waves 1..3

    // Combined biases: wave0 lanes own column jt*16 + l15.
    float bsi = 0.f, bsf = 0.f, bsg = 0.f, bso = 0.f;
    if (wave == 0) {
        const int j = jt * 16 + l15;
        const float* bi = layer ? bih1 : bih0;
        const float* bh = layer ? bhh1 : bhh0;
        bsi = bi[j]        + bh[j];
        bsf = bi[512 + j]  + bh[512 + j];
        bsg = bi[1024 + j] + bh[1024 + j];
        bso = bi[1536 + j] + bh[1536 + j];
    }

    float cst[4] = {0.f, 0.f, 0.f, 0.f};  // cell state: 4 batch rows x 1 col / lane

    if (layer == 0) {
        // Layer 0: A = [x_t (K 0..63) | h0_{s-1} (K 64..575)], 18 chunks of 32.
        const int cstart = (wave < 2) ? wave * 5 : 10 + (wave - 2) * 4;
        const int cnt_c  = (wave < 2) ? 5 : 4;
        half8 bf[4][5];
        #pragma unroll
        for (int g = 0; g < 4; ++g) {
            const int n = g * 512 + jt * 16 + l15;   // gate row (i,f,g,o)
            #pragma unroll
            for (int cc = 0; cc < 5; ++cc) {
                if (cc < cnt_c) {
                    const int c = cstart + cc;
                    const float* src = (c < 2)
                        ? (Wih0 + n * 64  + c * 32 + quad * 8)
                        : (Whh0 + n * 512 + (c - 2) * 32 + quad * 8);
                    bf[g][cc] = frag8(src);
                }
            }
        }

        for (int s = 0; s <= T_; ++s) {
            if (wave == 0) {
                wait_flags(f0, (unsigned)s, lane);                    // peers thru s-1
                if (s >= 2) wait_flags(f1, (unsigned)(s - 2), lane);  // ring0 anti-dep
            }
            __syncthreads();
            const bool active = (s < T_);
            floatx4 acc[4] = { {0.f,0.f,0.f,0.f}, {0.f,0.f,0.f,0.f},
                               {0.f,0.f,0.f,0.f}, {0.f,0.f,0.f,0.f} };
            if (active) {
                const float* h0prev = ring0 + ((s + R0S - 1) & (R0S - 1)) * SLOT; // slot (s-1)%4
                const int arow = mt * 16 + l15;
                #pragma unroll
                for (int cc = 0; cc < 5; ++cc) {
                    if (cc < cnt_c) {
                        const int c = cstart + cc;
                        half8 a;
                        if (c < 2) a = frag8(x + (arow * T_ + s) * DIN_ + c * 32 + quad * 8);
                        else       a = frag8_sys(h0prev + arow * H_ + (c - 2) * 32 + quad * 8);
                        acc[0] = __builtin_amdgcn_mfma_f32_16x16x32_f16(a, bf[0][cc], acc[0], 0, 0, 0);
                        acc[1] = __builtin_amdgcn_mfma_f32_16x16x32_f16(a, bf[1][cc], acc[1], 0, 0, 0);
                        acc[2] = __builtin_amdgcn_mfma_f32_16x16x32_f16(a, bf[2][cc], acc[2], 0, 0, 0);
                        acc[3] = __builtin_amdgcn_mfma_f32_16x16x32_f16(a, bf[3][cc], acc[3], 0, 0, 0);
                    }
                }
                if (wave != 0) {
                    #pragma unroll
                    for (int g = 0; g < 4; ++g)
                        #pragma unroll
                        for (int r = 0; r < 4; ++r)
                            red[wave - 1][g][r][lane] = acc[g][r];
                }
            }
            __syncthreads();
            if (wave == 0) {
                if (active) {
                    #pragma unroll
                    for (int g = 0; g < 4; ++g)
                        #pragma unroll
                        for (int r = 0; r < 4; ++r)
                            acc[g][r] += red[0][g][r][lane] + red[1][g][r][lane] + red[2][g][r][lane];
                    float* hdst = ring0 + (s & (R0S - 1)) * SLOT;
                    #pragma unroll
                    for (int r = 0; r < 4; ++r) {
                        const float ig = sigf(acc[0][r] + bsi);
                        const float fg = sigf(acc[1][r] + bsf);
                        const float gg = tanhf_(acc[2][r] + bsg);
                        const float og = sigf(acc[3][r] + bso);
                        const float cn = fg * cst[r] + ig * gg;
                        cst[r] = cn;
                        st_sys(hdst + (mt * 16 + quad * 4 + r) * H_ + jt * 16 + l15,
                               og * tanhf_(cn));
                    }
                }
                asm volatile("s_waitcnt vmcnt(0)" ::: "memory");  // drain wave0's h stores
                if (lane == 0) st_sys_u(f0 + jt, (unsigned)(s + 1));
            }
        }
    } else {
        // Layer 1 at tau = s-1: A = [h0_tau (K 0..511) | h1_{tau-1} (K 512..1023)].
        // Wave chunk split: waves 0-1 -> c 0..15 (pure h0); waves 2-3 -> c 16..31 (pure h1).
        half8 bf[4][8];
        #pragma unroll
        for (int g = 0; g < 4; ++g) {
            const int n = g * 512 + jt * 16 + l15;
            #pragma unroll
            for (int cc = 0; cc < 8; ++cc) {
                const int c = wave * 8 + cc;              // 0..31
                const float* src = (c < 16)
                    ? (Wih1 + n * 512 + c * 32 + quad * 8)
                    : (Whh1 + n * 512 + (c - 16) * 32 + quad * 8);
                bf[g][cc] = frag8(src);
            }
        }

        for (int s = 0; s <= T_; ++s) {
            const bool active = (s >= 1);
            const int tau = s - 1;
            const int arow = mt * 16 + l15;
            if (wave == 0) wait_flags(f0, (unsigned)s, lane);  // h0[tau] ready (early via lookahead)
            __syncthreads();   // A
            floatx4 acc[4] = { {0.f,0.f,0.f,0.f}, {0.f,0.f,0.f,0.f},
                               {0.f,0.f,0.f,0.f}, {0.f,0.f,0.f,0.f} };
            if (active && wave < 2) {
                const float* rb0 = ring0 + (tau & (R0S - 1)) * SLOT + arow * H_;
                #pragma unroll
                for (int cc = 0; cc < 8; ++cc) {
                    const int c = wave * 8 + cc;
                    const half8 a = frag8_sys(rb0 + c * 32 + quad * 8);
                    acc[0] = __builtin_amdgcn_mfma_f32_16x16x32_f16(a, bf[0][cc], acc[0], 0, 0, 0);
                    acc[1] = __builtin_amdgcn_mfma_f32_16x16x32_f16(a, bf[1][cc], acc[1], 0, 0, 0);
                    acc[2] = __builtin_amdgcn_mfma_f32_16x16x32_f16(a, bf[2][cc], acc[2], 0, 0, 0);
                    acc[3] = __builtin_amdgcn_mfma_f32_16x16x32_f16(a, bf[3][cc], acc[3], 0, 0, 0);
                }
                if (wave == 1) {
                    #pragma unroll
                    for (int g = 0; g < 4; ++g)
                        #pragma unroll
                        for (int r = 0; r < 4; ++r)
                            red[0][g][r][lane] = acc[g][r];
                }
            }
            if (wave == 0) wait_flags(f1, (unsigned)s, lane);  // h1[tau-1] ready (critical chain)
            __syncthreads();   // B
            if (active && wave >= 2) {
                const float* rb1 = ring1 + ((tau + 1) & 1) * SLOT + arow * H_;
                #pragma unroll
                for (int cc = 0; cc < 8; ++cc) {
                    const int c = wave * 8 + cc;
                    const half8 a = frag8_sys(rb1 + (c - 16) * 32 + quad * 8);
                    acc[0] = __builtin_amdgcn_mfma_f32_16x16x32_f16(a, bf[0][cc], acc[0], 0, 0, 0);
                    acc[1] = __builtin_amdgcn_mfma_f32_16x16x32_f16(a, bf[1][cc], acc[1], 0, 0, 0);
                    acc[2] = __builtin_amdgcn_mfma_f32_16x16x32_f16(a, bf[2][cc], acc[2], 0, 0, 0);
                    acc[3] = __builtin_amdgcn_mfma_f32_16x16x32_f16(a, bf[3][cc], acc[3], 0, 0, 0);
                }
                #pragma unroll
                for (int g = 0; g < 4; ++g)
                    #pragma unroll
                    for (int r = 0; r < 4; ++r)
                        red[wave - 1][g][r][lane] = acc[g][r];
            }
            __syncthreads();   // C
            if (wave == 0) {
                if (active) {
                    #pragma unroll
                    for (int g = 0; g < 4; ++g)
                        #pragma unroll
                        for (int r = 0; r < 4; ++r)
                            acc[g][r] += red[0][g][r][lane] + red[1][g][r][lane] + red[2][g][r][lane];
                    float* hdst = ring1 + (tau & 1) * SLOT;
                    #pragma unroll
                    for (int r = 0; r < 4; ++r) {
                        const float ig = sigf(acc[0][r] + bsi);
                        const float fg = sigf(acc[1][r] + bsf);
                        const float gg = tanhf_(acc[2][r] + bsg);
                        const float og = sigf(acc[3][r] + bso);
                        const float cn = fg * cst[r] + ig * gg;
                        cst[r] = cn;
                        st_sys(hdst + (mt * 16 + quad * 4 + r) * H_ + jt * 16 + l15,
                               og * tanhf_(cn));
                    }
                }
                asm volatile("s_waitcnt vmcnt(0)" ::: "memory");
                if (lane == 0) st_sys_u(f1 + jt, (unsigned)(s + 1));
            }
        }
    }

    // Wait for ALL layer-1 groups (epilogue reads h1_511 rows from every mt).
    // Each wave ballot-polls one group's L1 flag line.
    wait_flags(bar + ((4 + wave) << 6), (unsigned)(T_ + 1), lane);
    __syncthreads();

    // Epilogue: y[b][d] = h1_511[b][:] . Wout[d][:] + bout[d]  (fp32 out).
    // h1_511 = ring1 slot (511&1)=1; read via system-scope loads.
    {
        const float* h1fin = ring1 + SLOT;
        const int gid = blk * NTHR + tid;   // 0..65535
        const int o   = gid >> 5;           // 0..2047
        const int sub = gid & 31;
        const int ob  = o >> 5;
        const int od  = o & 31;
        float p = 0.f;
        const float* hb = h1fin + ob * H_ + sub * 16;
        const float* wb = Wout  + od * H_ + sub * 16;
        #pragma unroll
        for (int k = 0; k < 16; ++k)
            p += __hip_atomic_load(hb + k, __ATOMIC_RELAXED, __HIP_MEMORY_SCOPE_SYSTEM) * wb[k];
        p += __shfl_xor(p, 16);
        p += __shfl_xor(p, 8);
        p += __shfl_xor(p, 4);
        p += __shfl_xor(p, 2);
        p += __shfl_xor(p, 1);
        if (sub == 0) out[o] = p + bout[od];
    }
}

extern "C" void kernel_launch(void* const* d_in, const int* in_sizes, int n_in,
                              void* d_out, int out_size, void* d_ws, size_t ws_size,
                              hipStream_t stream) {
    (void)in_sizes; (void)n_in; (void)out_size; (void)ws_size;
    const float* x    = (const float*)d_in[0];
    const float* Wih0 = (const float*)d_in[1];
    const float* Whh0 = (const float*)d_in[2];
    const float* bih0 = (const float*)d_in[3];
    const float* bhh0 = (const float*)d_in[4];
    const float* Wih1 = (const float*)d_in[5];
    const float* Whh1 = (const float*)d_in[6];
    const float* bih1 = (const float*)d_in[7];
    const float* bhh1 = (const float*)d_in[8];
    const float* Wout = (const float*)d_in[9];
    const float* bout = (const float*)d_in[10];

    unsigned char* ws = (unsigned char*)d_ws;
    unsigned* bar = (unsigned*)ws;                        // 4 KB: 8 flag lines, 256B apart
    float* ring0  = (float*)(ws + 4096);                  // R0S slots x 128 KB
    float* ring1  = (float*)(ws + 4096 + R0S * SLOT * 4); // 2 slots x 128 KB
    // Zero flags + rings (ring0 slot3 and ring1 slot1 must read as h_{-1}=0).
    hipMemsetAsync(ws, 0, 4096 + (R0S + 2) * SLOT * 4, stream);

    lstm_v17<<<dim3(NBLK), dim3(NTHR), 0, stream>>>(
        x, Wih0, Whh0, bih0, bhh0, Wih1, Whh1, bih1, bhh1, Wout, bout,
        (float*)d_out, bar, ring0, ring1);
}

// Round 5
// 5117.692 us; speedup vs baseline: 2.9340x; 1.0408x over previous
//
#include <hip/hip_runtime.h>

// LSTMDynamics v18: B=64, T=512, D_IN=64, H=512, D_OUT=32.
// Same proven math as v14-v17. Change: XCD-PINNED groups + scope split.
//
// v17 left 10.4us/step with WRITE_SIZE == all ring stores hitting HBM:
// SYSTEM-scope (sc0 sc1) data path means every store-ack (vmcnt drain),
// flag poll, and h-load is a MALL/fabric round trip, on BOTH serial chains.
//
// v18: remap blk -> (layer=(blk&7)>>2, mt=blk&3, jt=blk>>3). With the
// measured round-robin dispatch (xcd = blk%8), each (layer,mt) group's 32
// blocks land on ONE XCD -> the group self-loop runs in XCD-local L2 with
// AGENT-scope (sc0) accesses: ~5x lower store-ack/poll/load latency, no HBM
// write-through. Cross-group edges stay sys-scope (latency-tolerant):
//   - h0 is dual-stored: agent copy (ring0a, L0 peers) + sys copy (ring0s,
//     read by L1; L1 lags L0 by up to 2 steps, absorbing the MALL trail).
//   - L1 publishes f1 both agent (its peers) and sys (L0's anti-dep poll).
//   - epilogue uses a dedicated sys-scope h1fin buffer + final flags.
// SAFETY (G16: dispatch mapping is undefined): at startup each block
// publishes its HW_REG_XCC_ID (sys scope); each group ballot-verifies all
// 32 peers share its XCD. On mismatch the group uses the v17 sys-scope path
// (fast flag unused). Decision is group-uniform -> scopes always consistent.
// L1 wait overlap: wave1 polls f0(sys) while wave0 polls f1(fast) -> one
// barrier, detection latencies overlap instead of serializing.
//
// Dependency algebra (flag value = completed iters; publish s+1 after drain):
//   L0@s: f0 >= s (peers thru s-1); s>=2: f1s >= s-2 (ring0s 4-slot anti-dep;
//         ring0a 2-slot anti-dep covered by f0 >= s).
//   L1@s (tau=s-1): f0s >= s (h0[tau] sys copy ready); f1 >= s (peers thru
//         s-1 + 2-slot ring1 anti-dep).
//   epilogue: fin[g] >= 1 for all g (published after final drain).

#define T_    512
#define B_    64
#define H_    512
#define DIN_  64
#define NBLK  256
#define NTHR  256
#define SLOT  (B_ * H_)   // 32768 fp32 per ring slot, layout [b][k]
#define LINE  64          // dwords per flag line (256B)

typedef _Float16 half8  __attribute__((ext_vector_type(8)));
typedef float    floatx4 __attribute__((ext_vector_type(4)));

__device__ inline float sigf(float x) { return 1.f / (1.f + __expf(-x)); }
__device__ inline float tanhf_(float x) {
    if (x >  9.f) return  1.f;
    if (x < -9.f) return -1.f;
    const float e = __expf(2.f * x);
    return (e - 1.f) / (e + 1.f);
}
__device__ inline float4 ld4(const float* p) { return *(const float4*)p; }

// fp32[8] -> fp16 MFMA fragment, normal cached path (weights, x).
__device__ inline half8 frag8(const float* p) {
    const float4 a = ld4(p), b = ld4(p + 4);
    half8 r;
    r[0] = (_Float16)a.x; r[1] = (_Float16)a.y; r[2] = (_Float16)a.z; r[3] = (_Float16)a.w;
    r[4] = (_Float16)b.x; r[5] = (_Float16)b.y; r[6] = (_Float16)b.z; r[7] = (_Float16)b.w;
    return r;
}

// Scope-explicit ring accessors.
__device__ inline half8 frag8_sys(const float* p) {
    float v[8];
    #pragma unroll
    for (int i = 0; i < 8; ++i)
        v[i] = __hip_atomic_load(p + i, __ATOMIC_RELAXED, __HIP_MEMORY_SCOPE_SYSTEM);
    half8 r;
    #pragma unroll
    for (int i = 0; i < 8; ++i) r[i] = (_Float16)v[i];
    return r;
}
__device__ inline half8 frag8_agt(const float* p) {
    float v[8];
    #pragma unroll
    for (int i = 0; i < 8; ++i)
        v[i] = __hip_atomic_load(p + i, __ATOMIC_RELAXED, __HIP_MEMORY_SCOPE_AGENT);
    half8 r;
    #pragma unroll
    for (int i = 0; i < 8; ++i) r[i] = (_Float16)v[i];
    return r;
}
__device__ inline float ld_sys_f(const float* p) {
    return __hip_atomic_load(p, __ATOMIC_RELAXED, __HIP_MEMORY_SCOPE_SYSTEM);
}
__device__ inline void st_sys(float* p, float v) {
    __hip_atomic_store(p, v, __ATOMIC_RELAXED, __HIP_MEMORY_SCOPE_SYSTEM);
}
__device__ inline void st_agt(float* p, float v) {
    __hip_atomic_store(p, v, __ATOMIC_RELAXED, __HIP_MEMORY_SCOPE_AGENT);
}
__device__ inline void st_sys_u(unsigned* p, unsigned v) {
    __hip_atomic_store(p, v, __ATOMIC_RELAXED, __HIP_MEMORY_SCOPE_SYSTEM);
}
__device__ inline void st_agt_u(unsigned* p, unsigned v) {
    __hip_atomic_store(p, v, __ATOMIC_RELAXED, __HIP_MEMORY_SCOPE_AGENT);
}
__device__ inline unsigned ld_sys_u(const unsigned* p) {
    return __hip_atomic_load(p, __ATOMIC_RELAXED, __HIP_MEMORY_SCOPE_SYSTEM);
}
__device__ inline unsigned ld_agt_u(const unsigned* p) {
    return __hip_atomic_load(p, __ATOMIC_RELAXED, __HIP_MEMORY_SCOPE_AGENT);
}

// Wave-parallel flag wait: 64 lanes read flags[lane&31] (one line), exit when
// every producer's flag >= tgt.
__device__ inline void wait_sys(unsigned* line, unsigned tgt, int lane) {
    for (;;) {
        const unsigned v = ld_sys_u(line + (lane & 31));
        if (__all((int)(v >= tgt))) return;
        __builtin_amdgcn_s_sleep(1);
    }
}
__device__ inline void wait_agt(unsigned* line, unsigned tgt, int lane) {
    for (;;) {
        const unsigned v = ld_agt_u(line + (lane & 31));
        if (__all((int)(v >= tgt))) return;
        __builtin_amdgcn_s_sleep(1);
    }
}

// MFMA 16x16x32 f16 fragment layout (proven by R2<->R5 bit-agreement):
//   A: a[j] = A[m = lane&15][k = (lane>>4)*8 + j]
//   B: b[j] = B[k = (lane>>4)*8 + j][n = lane&15]
//   D: d[r] = D[m = (lane>>4)*4 + r][n = lane&15]
__global__ __launch_bounds__(NTHR) void lstm_v18(
    const float* __restrict__ x,
    const float* __restrict__ Wih0, const float* __restrict__ Whh0,
    const float* __restrict__ bih0, const float* __restrict__ bhh0,
    const float* __restrict__ Wih1, const float* __restrict__ Whh1,
    const float* __restrict__ bih1, const float* __restrict__ bhh1,
    const float* __restrict__ Wout, const float* __restrict__ bout,
    float* __restrict__ out,
    unsigned* bar,
    float* ring0a,      // 2 slots (agent copy of h0, L0-local)
    float* ring0s,      // 4 slots (sys copy of h0, read by L1)
    float* ring1,       // 2 slots (h1; agent on fast path)
    float* h1fin)       // 1 slot  (final h1, sys, for epilogue)
{
    const int tid   = threadIdx.x;
    const int wave  = tid >> 6;
    const int lane  = tid & 63;
    const int l15   = lane & 15;
    const int quad  = lane >> 4;
    const int blk   = blockIdx.x;
    const int sel   = blk & 7;
    const int layer = sel >> 2;        // XCD-pinned decode: blk%8 selects group
    const int mt    = sel & 3;
    const int jt    = blk >> 3;        // 0..31

    unsigned* f0f = bar + (0  + mt) * LINE;   // L0 fast flags (agent)
    unsigned* f0s = bar + (4  + mt) * LINE;   // L0 sys flags
    unsigned* f1f = bar + (8  + mt) * LINE;   // L1 fast flags (agent)
    unsigned* f1s = bar + (12 + mt) * LINE;   // L1 sys flags
    // fin lines: 16+g ; xcd tables: 20+sel

    __shared__ float red[3][4][4][64]; // partials from waves 1..3
    __shared__ int s_fast;

    // ---- XCD verification (once): group-uniform fast/slow decision ----
    unsigned xcc;
    asm volatile("s_getreg_b32 %0, hwreg(HW_REG_XCC_ID)" : "=s"(xcc));
    {
        unsigned* xline = bar + (20 + sel) * LINE;
        if (wave == 0) {
            if (lane == 0) st_sys_u(xline + jt, xcc + 1u);
            unsigned v;
            for (;;) {
                v = ld_sys_u(xline + (lane & 31));
                if (__all((int)(v != 0u))) break;
                __builtin_amdgcn_s_sleep(1);
            }
            const int f = __all((int)(v == xcc + 1u));
            if (lane == 0) s_fast = f;
        }
        __syncthreads();
    }
    const bool fast = (s_fast != 0);

    // Combined biases: wave0 lanes own column jt*16 + l15.
    float bsi = 0.f, bsf = 0.f, bsg = 0.f, bso = 0.f;
    if (wave == 0) {
        const int j = jt * 16 + l15;
        const float* bi = layer ? bih1 : bih0;
        const float* bh = layer ? bhh1 : bhh0;
        bsi = bi[j]        + bh[j];
        bsf = bi[512 + j]  + bh[512 + j];
        bsg = bi[1024 + j] + bh[1024 + j];
        bso = bi[1536 + j] + bh[1536 + j];
    }

    float cst[4] = {0.f, 0.f, 0.f, 0.f};  // cell state: 4 batch rows x 1 col / lane

    if (layer == 0) {
        // Layer 0: A = [x_t (K 0..63) | h0_{s-1} (K 64..575)], 18 chunks of 32.
        const int cstart = (wave < 2) ? wave * 5 : 10 + (wave - 2) * 4;
        const int cnt_c  = (wave < 2) ? 5 : 4;
        half8 bf[4][5];
        #pragma unroll
        for (int g = 0; g < 4; ++g) {
            const int n = g * 512 + jt * 16 + l15;   // gate row (i,f,g,o)
            #pragma unroll
            for (int cc = 0; cc < 5; ++cc) {
                if (cc < cnt_c) {
                    const int c = cstart + cc;
                    const float* src = (c < 2)
                        ? (Wih0 + n * 64  + c * 32 + quad * 8)
                        : (Whh0 + n * 512 + (c - 2) * 32 + quad * 8);
                    bf[g][cc] = frag8(src);
                }
            }
        }

        for (int s = 0; s <= T_; ++s) {
            // Overlapped waits: wave0 = own-group flags, wave1 = anti-dep.
            if (wave == 0) {
                if (fast) wait_agt(f0f, (unsigned)s, lane);
                else      wait_sys(f0s, (unsigned)s, lane);
            } else if (wave == 1) {
                if (s >= 2) wait_sys(f1s, (unsigned)(s - 2), lane);
            }
            __syncthreads();
            const bool active = (s < T_);
            floatx4 acc[4] = { {0.f,0.f,0.f,0.f}, {0.f,0.f,0.f,0.f},
                               {0.f,0.f,0.f,0.f}, {0.f,0.f,0.f,0.f} };
            if (active) {
                const int arow = mt * 16 + l15;
                const float* h0a = ring0a + ((s + 1) & 1) * SLOT + arow * H_; // slot (s-1)&1
                const float* h0s = ring0s + ((s + 3) & 3) * SLOT + arow * H_; // slot (s-1)&3
                #pragma unroll
                for (int cc = 0; cc < 5; ++cc) {
                    if (cc < cnt_c) {
                        const int c = cstart + cc;
                        half8 a;
                        if (c < 2)      a = frag8(x + (arow * T_ + s) * DIN_ + c * 32 + quad * 8);
                        else if (fast)  a = frag8_agt(h0a + (c - 2) * 32 + quad * 8);
                        else            a = frag8_sys(h0s + (c - 2) * 32 + quad * 8);
                        acc[0] = __builtin_amdgcn_mfma_f32_16x16x32_f16(a, bf[0][cc], acc[0], 0, 0, 0);
                        acc[1] = __builtin_amdgcn_mfma_f32_16x16x32_f16(a, bf[1][cc], acc[1], 0, 0, 0);
                        acc[2] = __builtin_amdgcn_mfma_f32_16x16x32_f16(a, bf[2][cc], acc[2], 0, 0, 0);
                        acc[3] = __builtin_amdgcn_mfma_f32_16x16x32_f16(a, bf[3][cc], acc[3], 0, 0, 0);
                    }
                }
                if (wave != 0) {
                    #pragma unroll
                    for (int g = 0; g < 4; ++g)
                        #pragma unroll
                        for (int r = 0; r < 4; ++r)
                            red[wave - 1][g][r][lane] = acc[g][r];
                }
            }
            __syncthreads();
            if (wave == 0) {
                if (active) {
                    #pragma unroll
                    for (int g = 0; g < 4; ++g)
                        #pragma unroll
                        for (int r = 0; r < 4; ++r)
                            acc[g][r] += red[0][g][r][lane] + red[1][g][r][lane] + red[2][g][r][lane];
                    float* da = ring0a + (s & 1) * SLOT;
                    float* ds = ring0s + (s & 3) * SLOT;
                    #pragma unroll
                    for (int r = 0; r < 4; ++r) {
                        const float ig = sigf(acc[0][r] + bsi);
                        const float fg = sigf(acc[1][r] + bsf);
                        const float gg = tanhf_(acc[2][r] + bsg);
                        const float og = sigf(acc[3][r] + bso);
                        const float cn = fg * cst[r] + ig * gg;
                        cst[r] = cn;
                        const float hv = og * tanhf_(cn);
                        const int idx = (mt * 16 + quad * 4 + r) * H_ + jt * 16 + l15;
                        st_sys(ds + idx, hv);            // sys copy for L1
                        if (fast) st_agt(da + idx, hv);  // L2-local copy for L0 peers
                    }
                }
                asm volatile("s_waitcnt vmcnt(0)" ::: "memory");
                if (lane == 0) {
                    if (fast) st_agt_u(f0f + jt, (unsigned)(s + 1));
                    st_sys_u(f0s + jt, (unsigned)(s + 1));
                }
            }
        }
    } else {
        // Layer 1 at tau = s-1: A = [h0_tau (K 0..511) | h1_{tau-1} (K 512..1023)].
        // Waves 0-1 -> c 0..15 (h0 side), waves 2-3 -> c 16..31 (h1 side).
        half8 bf[4][8];
        #pragma unroll
        for (int g = 0; g < 4; ++g) {
            const int n = g * 512 + jt * 16 + l15;
            #pragma unroll
            for (int cc = 0; cc < 8; ++cc) {
                const int c = wave * 8 + cc;              // 0..31
                const float* src = (c < 16)
                    ? (Wih1 + n * 512 + c * 32 + quad * 8)
                    : (Whh1 + n * 512 + (c - 16) * 32 + quad * 8);
                bf[g][cc] = frag8(src);
            }
        }

        for (int s = 0; s <= T_; ++s) {
            const bool active = (s >= 1);
            const int tau = s - 1;
            const int arow = mt * 16 + l15;
            // Overlapped waits: wave0 = f1 (critical self-loop), wave1 = f0 (sys).
            if (wave == 0) {
                if (fast) wait_agt(f1f, (unsigned)s, lane);
                else      wait_sys(f1s, (unsigned)s, lane);
            } else if (wave == 1) {
                wait_sys(f0s, (unsigned)s, lane);
            }
            __syncthreads();
            floatx4 acc[4] = { {0.f,0.f,0.f,0.f}, {0.f,0.f,0.f,0.f},
                               {0.f,0.f,0.f,0.f}, {0.f,0.f,0.f,0.f} };
            if (active) {
                if (wave < 2) {
                    const float* rb0 = ring0s + (tau & 3) * SLOT + arow * H_;
                    #pragma unroll
                    for (int cc = 0; cc < 8; ++cc) {
                        const int c = wave * 8 + cc;
                        const half8 a = frag8_sys(rb0 + c * 32 + quad * 8);
                        acc[0] = __builtin_amdgcn_mfma_f32_16x16x32_f16(a, bf[0][cc], acc[0], 0, 0, 0);
                        acc[1] = __builtin_amdgcn_mfma_f32_16x16x32_f16(a, bf[1][cc], acc[1], 0, 0, 0);
                        acc[2] = __builtin_amdgcn_mfma_f32_16x16x32_f16(a, bf[2][cc], acc[2], 0, 0, 0);
                        acc[3] = __builtin_amdgcn_mfma_f32_16x16x32_f16(a, bf[3][cc], acc[3], 0, 0, 0);
                    }
                } else {
                    const float* rb1 = ring1 + ((tau + 1) & 1) * SLOT + arow * H_;
                    #pragma unroll
                    for (int cc = 0; cc < 8; ++cc) {
                        const int c = wave * 8 + cc;
                        const half8 a = fast ? frag8_agt(rb1 + (c - 16) * 32 + quad * 8)
                                             : frag8_sys(rb1 + (c - 16) * 32 + quad * 8);
                        acc[0] = __builtin_amdgcn_mfma_f32_16x16x32_f16(a, bf[0][cc], acc[0], 0, 0, 0);
                        acc[1] = __builtin_amdgcn_mfma_f32_16x16x32_f16(a, bf[1][cc], acc[1], 0, 0, 0);
                        acc[2] = __builtin_amdgcn_mfma_f32_16x16x32_f16(a, bf[2][cc], acc[2], 0, 0, 0);
                        acc[3] = __builtin_amdgcn_mfma_f32_16x16x32_f16(a, bf[3][cc], acc[3], 0, 0, 0);
                    }
                }
                if (wave != 0) {
                    #pragma unroll
                    for (int g = 0; g < 4; ++g)
                        #pragma unroll
                        for (int r = 0; r < 4; ++r)
                            red[wave - 1][g][r][lane] = acc[g][r];
                }
            }
            __syncthreads();
            if (wave == 0) {
                if (active) {
                    #pragma unroll
                    for (int g = 0; g < 4; ++g)
                        #pragma unroll
                        for (int r = 0; r < 4; ++r)
                            acc[g][r] += red[0][g][r][lane] + red[1][g][r][lane] + red[2][g][r][lane];
                    float* hd = ring1 + (tau & 1) * SLOT;
                    #pragma unroll
                    for (int r = 0; r < 4; ++r) {
                        const float ig = sigf(acc[0][r] + bsi);
                        const float fg = sigf(acc[1][r] + bsf);
                        const float gg = tanhf_(acc[2][r] + bsg);
                        const float og = sigf(acc[3][r] + bso);
                        const float cn = fg * cst[r] + ig * gg;
                        cst[r] = cn;
                        const float hv = og * tanhf_(cn);
                        const int idx = (mt * 16 + quad * 4 + r) * H_ + jt * 16 + l15;
                        if (fast) st_agt(hd + idx, hv);
                        else      st_sys(hd + idx, hv);
                        if (tau == T_ - 1) st_sys(h1fin + idx, hv);  // epilogue copy
                    }
                }
                asm volatile("s_waitcnt vmcnt(0)" ::: "memory");
                if (lane == 0) {
                    if (fast) st_agt_u(f1f + jt, (unsigned)(s + 1));
                    st_sys_u(f1s + jt, (unsigned)(s + 1));
                }
            }
        }
        // Final publish: h1fin drained by the s=T_ iteration's vmcnt(0).
        if (wave == 0 && lane == 0) st_sys_u(bar + (16 + mt) * LINE + jt, 1u);
    }

    // Wait for ALL groups' final flags (epilogue reads h1fin from every mt).
    wait_sys(bar + (16 + wave) * LINE, 1u, lane);
    __syncthreads();

    // Epilogue: y[b][d] = h1_511[b][:] . Wout[d][:] + bout[d]  (fp32 out).
    {
        const int gid = blk * NTHR + tid;   // 0..65535
        const int o   = gid >> 5;           // 0..2047
        const int sub = gid & 31;
        const int ob  = o >> 5;
        const int od  = o & 31;
        float p = 0.f;
        const float* hb = h1fin + ob * H_ + sub * 16;
        const float* wb = Wout  + od * H_ + sub * 16;
        #pragma unroll
        for (int k = 0; k < 16; ++k) p += ld_sys_f(hb + k) * wb[k];
        p += __shfl_xor(p, 16);
        p += __shfl_xor(p, 8);
        p += __shfl_xor(p, 4);
        p += __shfl_xor(p, 2);
        p += __shfl_xor(p, 1);
        if (sub == 0) out[o] = p + bout[od];
    }
}

extern "C" void kernel_launch(void* const* d_in, const int* in_sizes, int n_in,
                              void* d_out, int out_size, void* d_ws, size_t ws_size,
                              hipStream_t stream) {
    (void)in_sizes; (void)n_in; (void)out_size; (void)ws_size;
    const float* x    = (const float*)d_in[0];
    const float* Wih0 = (const float*)d_in[1];
    const float* Whh0 = (const float*)d_in[2];
    const float* bih0 = (const float*)d_in[3];
    const float* bhh0 = (const float*)d_in[4];
    const float* Wih1 = (const float*)d_in[5];
    const float* Whh1 = (const float*)d_in[6];
    const float* bih1 = (const float*)d_in[7];
    const float* bhh1 = (const float*)d_in[8];
    const float* Wout = (const float*)d_in[9];
    const float* bout = (const float*)d_in[10];

    unsigned char* ws = (unsigned char*)d_ws;
    unsigned* bar  = (unsigned*)ws;              // 8 KB: 28 flag/xcd lines, 256B apart
    float* ring0a  = (float*)(ws + 8192);        // 2 slots x 128 KB (agent h0)
    float* ring0s  = ring0a + 2 * SLOT;          // 4 slots x 128 KB (sys h0)
    float* ring1   = ring0s + 4 * SLOT;          // 2 slots x 128 KB (h1)
    float* h1fin   = ring1  + 2 * SLOT;          // 1 slot  x 128 KB (final h1)
    // Zero flags + xcd tables + rings (slots holding h_{-1} must read 0).
    (void)hipMemsetAsync(ws, 0, 8192 + 9 * SLOT * 4, stream);

    lstm_v18<<<dim3(NBLK), dim3(NTHR), 0, stream>>>(
        x, Wih0, Whh0, bih0, bhh0, Wih1, Whh1, bih1, bhh1, Wout, bout,
        (float*)d_out, bar, ring0a, ring0s, ring1, h1fin);
}